// Round 2
// baseline (832.142 us; speedup 1.0000x reference)
//
#include <hip/hip_runtime.h>
#include <stdint.h>

#define NN 100000
#define NE 400000
#define FIN 602
#define HID 256
#define NC 42
#define NB_SCAN 98   // ceil(NN/1024)

typedef __attribute__((ext_vector_type(8))) short bf16x8;
typedef __attribute__((ext_vector_type(4))) float f32x4;
typedef __attribute__((ext_vector_type(2))) float f32x2;
typedef __attribute__((ext_vector_type(4))) short s16x4;

static __device__ __forceinline__ short f2bf(float f) {
  union { float f; uint32_t u; } v; v.f = f;
  uint32_t r = (v.u + 0x7fffu + ((v.u >> 16) & 1u)) >> 16;
  return (short)(uint16_t)r;
}
static __device__ __forceinline__ float bf2f(short s) {
  union { uint32_t u; float f; } v; v.u = ((uint32_t)(uint16_t)s) << 16;
  return v.f;
}

// ---------------- degree count ----------------
__global__ __launch_bounds__(256) void k_count(const int* __restrict__ dst, int* __restrict__ cnt) {
  int t = blockIdx.x * 256 + threadIdx.x;
  if (t < NE) atomicAdd(&cnt[dst[t]], 1);
}

// ---------------- scan: rowptr = exclusive prefix of cnt ----------------
__global__ __launch_bounds__(1024) void k_scan_local(const int* __restrict__ cnt, int* __restrict__ rowptr,
                                                     int* __restrict__ bsum) {
  __shared__ int sm[1024];
  int tid = threadIdx.x, t = blockIdx.x * 1024 + tid;
  int v = (t < NN) ? cnt[t] : 0;
  sm[tid] = v;
  __syncthreads();
  for (int off = 1; off < 1024; off <<= 1) {
    int y = (tid >= off) ? sm[tid - off] : 0;
    __syncthreads();
    sm[tid] += y;
    __syncthreads();
  }
  if (t < NN) rowptr[t] = sm[tid] - v;  // local exclusive
  if (tid == 1023) bsum[blockIdx.x] = sm[tid];
}
__global__ __launch_bounds__(128) void k_scan_bsum(int* __restrict__ bsum) {
  __shared__ int sm[128];
  int tid = threadIdx.x;
  int v = (tid < NB_SCAN) ? bsum[tid] : 0;
  sm[tid] = v;
  __syncthreads();
  for (int off = 1; off < 128; off <<= 1) {
    int y = (tid >= off) ? sm[tid - off] : 0;
    __syncthreads();
    sm[tid] += y;
    __syncthreads();
  }
  if (tid < NB_SCAN) bsum[tid] = sm[tid] - v;  // exclusive
}
__global__ __launch_bounds__(1024) void k_scan_add(int* __restrict__ rowptr, const int* __restrict__ bsum) {
  int t = blockIdx.x * 1024 + threadIdx.x;
  if (t < NN) rowptr[t] += bsum[t >> 10];
  if (t == 0) rowptr[NN] = NE;
}

// ---------------- bucket sort edges by dst: esorted[j] = src ----------------
__global__ __launch_bounds__(256) void k_sort(const int* __restrict__ src, const int* __restrict__ dst,
                                              const int* __restrict__ rowptr, int* __restrict__ epos,
                                              int* __restrict__ esorted) {
  int t = blockIdx.x * 256 + threadIdx.x;
  if (t >= NE) return;
  int d = dst[t];
  int p = atomicAdd(&epos[d], 1);
  esorted[rowptr[d] + p] = src[t];
}

// ------------- weight prep: fragment-ordered bf16 -------------
// wf[(((ct*19)+ks)*64 + lane)*8 + i] = W[k = ks*32 + (lane>>4)*8 + i][c = ct*16 + (lane&15)]
// ct in [0,16): Wl (cols 0..255); ct in [16,32): Wr (cols 256..511)
__global__ __launch_bounds__(256) void k_prep_w1(const float* __restrict__ Wl, const float* __restrict__ Wr,
                                                 short* __restrict__ wf) {
  int idx = blockIdx.x * 256 + threadIdx.x;
  if (idx >= 32 * 19 * 512) return;
  int i = idx & 7, l = (idx >> 3) & 63, rest = idx >> 9;
  int ks = rest % 19, ct = rest / 19;
  int c = ct * 16 + (l & 15);
  int k = ks * 32 + ((l >> 4) << 3) + i;
  float v = 0.f;
  if (k < FIN) v = (c < HID) ? Wl[k * HID + c] : Wr[k * HID + (c - HID)];
  wf[idx] = f2bf(v);
}
__global__ __launch_bounds__(256) void k_prep_w2(const float* __restrict__ Wl, const float* __restrict__ Wr,
                                                 short* __restrict__ wf) {
  int idx = blockIdx.x * 256 + threadIdx.x;
  if (idx >= 6 * 8 * 512) return;
  int i = idx & 7, l = (idx >> 3) & 63, rest = idx >> 9;
  int ks = rest & 7, ct = rest >> 3;
  int c = ct * 16 + (l & 15);
  int k = ks * 32 + ((l >> 4) << 3) + i;
  float v = 0.f;
  if (c < NC) v = Wl[k * NC + c];
  else if (c < 2 * NC) v = Wr[k * NC + (c - NC)];
  wf[idx] = f2bf(v);
}

// ---------------- layer-1 GEMM over x (two passes share code) ----------------
// PASS 0: t1 = bf16(x @ Wl1)             (outb = t1, hag unused)
// PASS 1: hbuf = relu(x @ Wr1 + hag)     (outb = hbuf)
// block: 4 waves, BM=32 rows, 256 cols; wave w owns cols [w*64, w*64+64)
template <int PASS>
__global__ __launch_bounds__(256) void k_gemmx(const float* __restrict__ x, const short* __restrict__ wf,
                                               const short* __restrict__ hag, short* __restrict__ outb) {
  const int lane = threadIdx.x & 63;
  const int w = threadIdx.x >> 6;
  const int lr = lane & 15, lg = lane >> 4;
  const int row0 = blockIdx.x * 32;

  f32x4 acc[2][4];
#pragma unroll
  for (int a = 0; a < 2; ++a)
#pragma unroll
    for (int b = 0; b < 4; ++b)
      acc[a][b] = (f32x4){0.f, 0.f, 0.f, 0.f};

  const float* xr0 = x + (size_t)(row0 + lr) * FIN + lg * 8;
  const float* xr1 = xr0 + (size_t)16 * FIN;
  const int ctb = (PASS == 0 ? 0 : 16) + w * 4;
  const short* wb = wf + (size_t)ctb * 19 * 512 + lane * 8;

  for (int ks = 0; ks < 19; ++ks) {
    bf16x8 a0, a1;
    if (ks < 18) {
      const float* p0 = xr0 + ks * 32;
      const float* p1 = xr1 + ks * 32;
#pragma unroll
      for (int i = 0; i < 4; ++i) {
        f32x2 u0 = *(const f32x2*)(p0 + 2 * i);
        f32x2 u1 = *(const f32x2*)(p1 + 2 * i);
        a0[2 * i] = f2bf(u0[0]); a0[2 * i + 1] = f2bf(u0[1]);
        a1[2 * i] = f2bf(u1[0]); a1[2 * i + 1] = f2bf(u1[1]);
      }
    } else {
      const float* p0 = xr0 + 576;
      const float* p1 = xr1 + 576;
      int kb = 576 + lg * 8;
#pragma unroll
      for (int i = 0; i < 8; ++i) {
        bool ok = (kb + i) < FIN;
        a0[i] = ok ? f2bf(p0[i]) : (short)0;
        a1[i] = ok ? f2bf(p1[i]) : (short)0;
      }
    }
    bf16x8 bfrag[4];
#pragma unroll
    for (int ct = 0; ct < 4; ++ct)
      bfrag[ct] = *(const bf16x8*)(wb + (size_t)(ct * 19 + ks) * 512);
#pragma unroll
    for (int ct = 0; ct < 4; ++ct) {
      acc[0][ct] = __builtin_amdgcn_mfma_f32_16x16x32_bf16(a0, bfrag[ct], acc[0][ct], 0, 0, 0);
      acc[1][ct] = __builtin_amdgcn_mfma_f32_16x16x32_bf16(a1, bfrag[ct], acc[1][ct], 0, 0, 0);
    }
  }
#pragma unroll
  for (int rt = 0; rt < 2; ++rt)
#pragma unroll
    for (int ct = 0; ct < 4; ++ct)
#pragma unroll
      for (int j = 0; j < 4; ++j) {
        int row = row0 + rt * 16 + lg * 4 + j;
        int col = w * 64 + ct * 16 + lr;
        size_t off = (size_t)row * HID + col;
        if (PASS == 0) {
          outb[off] = f2bf(acc[rt][ct][j]);
        } else {
          float v = acc[rt][ct][j] + bf2f(hag[off]);
          outb[off] = f2bf(v > 0.f ? v : 0.f);
        }
      }
}

// ---------------- gather1: hag[n] = mean(t1[neighbors]) + bl1 (bf16) ----------------
__global__ __launch_bounds__(256) void k_gather1(const short* __restrict__ t1, const int* __restrict__ rowptr,
                                                 const int* __restrict__ esorted, const float* __restrict__ bl,
                                                 short* __restrict__ hag) {
  int t = blockIdx.x * 256 + threadIdx.x;
  int n = t >> 6, lane = t & 63;
  if (n >= NN) return;
  int beg = rowptr[n], end = rowptr[n + 1];
  float a0 = 0.f, a1 = 0.f, a2 = 0.f, a3 = 0.f;
  for (int j = beg; j < end; ++j) {
    int s = esorted[j];
    s16x4 v = *(const s16x4*)(t1 + (size_t)s * HID + lane * 4);
    a0 += bf2f(v[0]); a1 += bf2f(v[1]); a2 += bf2f(v[2]); a3 += bf2f(v[3]);
  }
  int deg = end - beg;
  float inv = 1.0f / (float)(deg > 1 ? deg : 1);
  f32x4 b = *(const f32x4*)(bl + lane * 4);
  s16x4 o;
  o[0] = f2bf(a0 * inv + b[0]);
  o[1] = f2bf(a1 * inv + b[1]);
  o[2] = f2bf(a2 * inv + b[2]);
  o[3] = f2bf(a3 * inv + b[3]);
  *(s16x4*)(hag + (size_t)n * HID + lane * 4) = o;
}

// ---------------- GEMM2: u[N,96] = h[N,256] @ [Wl2|Wr2] (cols 84..95 pad) ----------------
__global__ __launch_bounds__(256) void k_gemm2(const short* __restrict__ h, const short* __restrict__ wf,
                                               float* __restrict__ u) {
  const int lane = threadIdx.x & 63;
  const int w = threadIdx.x >> 6;
  const int lr = lane & 15, lg = lane >> 4;
  const int row0 = blockIdx.x * 128 + w * 32;

  f32x4 acc[2][6];
#pragma unroll
  for (int a = 0; a < 2; ++a)
#pragma unroll
    for (int b = 0; b < 6; ++b)
      acc[a][b] = (f32x4){0.f, 0.f, 0.f, 0.f};

  const int r0 = row0 + lr, r1 = row0 + 16 + lr;
  for (int ks = 0; ks < 8; ++ks) {
    bf16x8 a0, a1;
#pragma unroll
    for (int i = 0; i < 8; ++i) { a0[i] = 0; a1[i] = 0; }
    if (r0 < NN) a0 = *(const bf16x8*)(h + (size_t)r0 * HID + ks * 32 + lg * 8);
    if (r1 < NN) a1 = *(const bf16x8*)(h + (size_t)r1 * HID + ks * 32 + lg * 8);
    bf16x8 bfrag[6];
#pragma unroll
    for (int ct = 0; ct < 6; ++ct)
      bfrag[ct] = *(const bf16x8*)(wf + (size_t)((ct * 8 + ks) * 64 + lane) * 8);
#pragma unroll
    for (int ct = 0; ct < 6; ++ct) {
      acc[0][ct] = __builtin_amdgcn_mfma_f32_16x16x32_bf16(a0, bfrag[ct], acc[0][ct], 0, 0, 0);
      acc[1][ct] = __builtin_amdgcn_mfma_f32_16x16x32_bf16(a1, bfrag[ct], acc[1][ct], 0, 0, 0);
    }
  }
#pragma unroll
  for (int rt = 0; rt < 2; ++rt)
#pragma unroll
    for (int ct = 0; ct < 6; ++ct)
#pragma unroll
      for (int j = 0; j < 4; ++j) {
        int row = row0 + rt * 16 + lg * 4 + j;
        int col = ct * 16 + lr;
        if (row < NN) u[(size_t)row * 96 + col] = acc[rt][ct][j];
      }
}

// ---------------- final: log_softmax(mean(u[nbrs,0:42]) + bl2 + u[:,42:84]) ----------------
__global__ __launch_bounds__(256) void k_final(const float* __restrict__ u, const int* __restrict__ rowptr,
                                               const int* __restrict__ esorted, const float* __restrict__ bl,
                                               float* __restrict__ out) {
  int t = blockIdx.x * 256 + threadIdx.x;
  int n = t >> 6, c = t & 63;
  if (n >= NN) return;
  int beg = rowptr[n], end = rowptr[n + 1];
  float a = 0.f;
  if (c < NC) {
    for (int j = beg; j < end; ++j) {
      int s = esorted[j];
      a += u[(size_t)s * 96 + c];
    }
  }
  int deg = end - beg;
  float inv = 1.0f / (float)(deg > 1 ? deg : 1);
  float v = (c < NC) ? (a * inv + bl[c] + u[(size_t)n * 96 + NC + c]) : -1e30f;
  float m = v;
#pragma unroll
  for (int off = 32; off > 0; off >>= 1) m = fmaxf(m, __shfl_xor(m, off));
  float e = (c < NC) ? __expf(v - m) : 0.f;
#pragma unroll
  for (int off = 32; off > 0; off >>= 1) e += __shfl_xor(e, off);
  float lse = __logf(e);
  if (c < NC) out[(size_t)n * NC + c] = v - m - lse;
}

extern "C" void kernel_launch(void* const* d_in, const int* in_sizes, int n_in,
                              void* d_out, int out_size, void* d_ws, size_t ws_size,
                              hipStream_t stream) {
  const float* x   = (const float*)d_in[0];
  const int* eidx  = (const int*)d_in[1];
  const float* Wl1 = (const float*)d_in[2];
  const float* bl1 = (const float*)d_in[3];
  const float* Wr1 = (const float*)d_in[4];
  const float* Wl2 = (const float*)d_in[5];
  const float* bl2 = (const float*)d_in[6];
  const float* Wr2 = (const float*)d_in[7];
  float* out = (float*)d_out;
  const int* src = eidx;
  const int* dstp = eidx + NE;

  // workspace layout (bytes) — peak 102.83 MiB
  char* ws = (char*)d_ws;
  int*   cnt     = (int*)(ws + 0);           //   400,000
  int*   rowptr  = (int*)(ws + 524288);      //   400,004
  int*   epos    = (int*)(ws + 1048576);     //   400,000
  int*   bsum    = (int*)(ws + 1462272);     //       392
  short* wf1     = (short*)(ws + 1572864);   //   622,592
  short* wf2     = (short*)(ws + 2359296);   //    49,152
  int*   esorted = (int*)(ws + 2621440);     // 1,600,000  (ends 4,221,440)
  short* t1      = (short*)(ws + 5242880);   // 51,200,000 (ends 56,442,880); later reused as hbuf
  short* hag     = (short*)(ws + 56623104);  // 51,200,000 (ends 107,823,104); later reused as u
  short* hbuf    = t1;                        // t1 dead after gather1
  float* u       = (float*)(ws + 56623104);  // 38,400,000 — hag dead after gemmx<1>

  hipMemsetAsync(cnt, 0, (size_t)NN * sizeof(int), stream);
  hipMemsetAsync(epos, 0, (size_t)NN * sizeof(int), stream);
  k_prep_w1<<<(32 * 19 * 512 + 255) / 256, 256, 0, stream>>>(Wl1, Wr1, wf1);
  k_prep_w2<<<(6 * 8 * 512 + 255) / 256, 256, 0, stream>>>(Wl2, Wr2, wf2);
  k_count<<<(NE + 255) / 256, 256, 0, stream>>>(dstp, cnt);
  k_scan_local<<<NB_SCAN, 1024, 0, stream>>>(cnt, rowptr, bsum);
  k_scan_bsum<<<1, 128, 0, stream>>>(bsum);
  k_scan_add<<<NB_SCAN, 1024, 0, stream>>>(rowptr, bsum);
  k_sort<<<(NE + 255) / 256, 256, 0, stream>>>(src, dstp, rowptr, epos, esorted);
  k_gemmx<0><<<NN / 32, 256, 0, stream>>>(x, wf1, (const short*)nullptr, t1);
  k_gather1<<<(NN * 64) / 256, 256, 0, stream>>>(t1, rowptr, esorted, bl1, hag);
  k_gemmx<1><<<NN / 32, 256, 0, stream>>>(x, wf1, hag, hbuf);
  k_gemm2<<<(NN + 127) / 128, 256, 0, stream>>>(hbuf, wf2, u);
  k_final<<<(NN * 64) / 256, 256, 0, stream>>>(u, rowptr, esorted, bl2, out);
}

// Round 4
// 817.685 us; speedup vs baseline: 1.0177x; 1.0177x over previous
//
#include <hip/hip_runtime.h>
#include <stdint.h>

#define NN 100000
#define NE 400000
#define FIN 602
#define HID 256
#define NC 42
#define NB_SCAN 98   // ceil(NN/1024)

typedef __attribute__((ext_vector_type(8))) short bf16x8;
typedef __attribute__((ext_vector_type(4))) float f32x4;
typedef __attribute__((ext_vector_type(2))) float f32x2;
typedef __attribute__((ext_vector_type(4))) short s16x4;

static __device__ __forceinline__ short f2bf(float f) {
  union { float f; uint32_t u; } v; v.f = f;
  uint32_t r = (v.u + 0x7fffu + ((v.u >> 16) & 1u)) >> 16;
  return (short)(uint16_t)r;
}
static __device__ __forceinline__ float bf2f(short s) {
  union { uint32_t u; float f; } v; v.u = ((uint32_t)(uint16_t)s) << 16;
  return v.f;
}
// HW packed f32->bf16 (RNE): dst.lo=cvt(a), dst.hi=cvt(b)
static __device__ __forceinline__ uint32_t cvtpk(float a, float b) {
  uint32_t r;
  asm("v_cvt_pk_bf16_f32 %0, %1, %2" : "=v"(r) : "v"(a), "v"(b));
  return r;
}
static __device__ __forceinline__ bf16x8 pack8(f32x2 a, f32x2 b, f32x2 c, f32x2 d) {
  union { bf16x8 v; uint32_t u[4]; } r;
  r.u[0] = cvtpk(a[0], a[1]);
  r.u[1] = cvtpk(b[0], b[1]);
  r.u[2] = cvtpk(c[0], c[1]);
  r.u[3] = cvtpk(d[0], d[1]);
  return r.v;
}

// ---------------- degree count ----------------
__global__ __launch_bounds__(256) void k_count(const int* __restrict__ dst, int* __restrict__ cnt) {
  int t = blockIdx.x * 256 + threadIdx.x;
  if (t < NE) atomicAdd(&cnt[dst[t]], 1);
}

// ---------------- scan: rowptr = exclusive prefix of cnt ----------------
__global__ __launch_bounds__(1024) void k_scan_local(const int* __restrict__ cnt, int* __restrict__ rowptr,
                                                     int* __restrict__ bsum) {
  __shared__ int sm[1024];
  int tid = threadIdx.x, t = blockIdx.x * 1024 + tid;
  int v = (t < NN) ? cnt[t] : 0;
  sm[tid] = v;
  __syncthreads();
  for (int off = 1; off < 1024; off <<= 1) {
    int y = (tid >= off) ? sm[tid - off] : 0;
    __syncthreads();
    sm[tid] += y;
    __syncthreads();
  }
  if (t < NN) rowptr[t] = sm[tid] - v;  // local exclusive
  if (tid == 1023) bsum[blockIdx.x] = sm[tid];
}
__global__ __launch_bounds__(128) void k_scan_bsum(int* __restrict__ bsum) {
  __shared__ int sm[128];
  int tid = threadIdx.x;
  int v = (tid < NB_SCAN) ? bsum[tid] : 0;
  sm[tid] = v;
  __syncthreads();
  for (int off = 1; off < 128; off <<= 1) {
    int y = (tid >= off) ? sm[tid - off] : 0;
    __syncthreads();
    sm[tid] += y;
    __syncthreads();
  }
  if (tid < NB_SCAN) bsum[tid] = sm[tid] - v;  // exclusive
}
__global__ __launch_bounds__(1024) void k_scan_add(int* __restrict__ rowptr, const int* __restrict__ bsum) {
  int t = blockIdx.x * 1024 + threadIdx.x;
  if (t < NN) rowptr[t] += bsum[t >> 10];
  if (t == 0) rowptr[NN] = NE;
}

// ---------------- bucket sort edges by dst: esorted[j] = src ----------------
__global__ __launch_bounds__(256) void k_sort(const int* __restrict__ src, const int* __restrict__ dst,
                                              const int* __restrict__ rowptr, int* __restrict__ epos,
                                              int* __restrict__ esorted) {
  int t = blockIdx.x * 256 + threadIdx.x;
  if (t >= NE) return;
  int d = dst[t];
  int p = atomicAdd(&epos[d], 1);
  esorted[rowptr[d] + p] = src[t];
}

// ------------- weight prep: fragment-ordered bf16 -------------
// wf[(((ct*19)+ks)*64 + lane)*8 + i] = W[k = ks*32 + (lane>>4)*8 + i][c = ct*16 + (lane&15)]
// ct in [0,16): Wl (cols 0..255); ct in [16,32): Wr (cols 256..511)
__global__ __launch_bounds__(256) void k_prep_w1(const float* __restrict__ Wl, const float* __restrict__ Wr,
                                                 short* __restrict__ wf) {
  int idx = blockIdx.x * 256 + threadIdx.x;
  if (idx >= 32 * 19 * 512) return;
  int i = idx & 7, l = (idx >> 3) & 63, rest = idx >> 9;
  int ks = rest % 19, ct = rest / 19;
  int c = ct * 16 + (l & 15);
  int k = ks * 32 + ((l >> 4) << 3) + i;
  float v = 0.f;
  if (k < FIN) v = (c < HID) ? Wl[k * HID + c] : Wr[k * HID + (c - HID)];
  wf[idx] = f2bf(v);
}
__global__ __launch_bounds__(256) void k_prep_w2(const float* __restrict__ Wl, const float* __restrict__ Wr,
                                                 short* __restrict__ wf) {
  int idx = blockIdx.x * 256 + threadIdx.x;
  if (idx >= 6 * 8 * 512) return;
  int i = idx & 7, l = (idx >> 3) & 63, rest = idx >> 9;
  int ks = rest & 7, ct = rest >> 3;
  int c = ct * 16 + (l & 15);
  int k = ks * 32 + ((l >> 4) << 3) + i;
  float v = 0.f;
  if (c < NC) v = Wl[k * NC + c];
  else if (c < 2 * NC) v = Wr[k * NC + (c - NC)];
  wf[idx] = f2bf(v);
}

// ---------------- pass 0: t1 = bf16(x @ Wl1), software-pipelined ----------------
// 4 waves; BM=32 rows; wave w owns cols [w*64, w*64+64)
__global__ __launch_bounds__(256) void k_gemm_l1a(const float* __restrict__ x, const short* __restrict__ wf,
                                                  short* __restrict__ t1) {
  const int lane = threadIdx.x & 63;
  const int w = threadIdx.x >> 6;
  const int lr = lane & 15, lg = lane >> 4;
  const int row0 = blockIdx.x * 32;

  f32x4 acc[2][4];
#pragma unroll
  for (int a = 0; a < 2; ++a)
#pragma unroll
    for (int b = 0; b < 4; ++b)
      acc[a][b] = (f32x4){0.f, 0.f, 0.f, 0.f};

  const float* xr0 = x + (size_t)(row0 + lr) * FIN + lg * 8;
  const float* xr1 = xr0 + (size_t)16 * FIN;
  const short* wb = wf + (size_t)(w * 4) * 19 * 512 + lane * 8;

  // prefetch ks=0 (f32x2 loads keep 8B alignment for every row)
  f32x2 n00 = *(const f32x2*)(xr0 + 0), n01 = *(const f32x2*)(xr0 + 2);
  f32x2 n02 = *(const f32x2*)(xr0 + 4), n03 = *(const f32x2*)(xr0 + 6);
  f32x2 n10 = *(const f32x2*)(xr1 + 0), n11 = *(const f32x2*)(xr1 + 2);
  f32x2 n12 = *(const f32x2*)(xr1 + 4), n13 = *(const f32x2*)(xr1 + 6);

#pragma unroll
  for (int ks = 0; ks < 18; ++ks) {
    f32x2 c00 = n00, c01 = n01, c02 = n02, c03 = n03;
    f32x2 c10 = n10, c11 = n11, c12 = n12, c13 = n13;
    if (ks < 17) {
      const float* p0 = xr0 + (ks + 1) * 32;
      const float* p1 = xr1 + (ks + 1) * 32;
      n00 = *(const f32x2*)(p0 + 0); n01 = *(const f32x2*)(p0 + 2);
      n02 = *(const f32x2*)(p0 + 4); n03 = *(const f32x2*)(p0 + 6);
      n10 = *(const f32x2*)(p1 + 0); n11 = *(const f32x2*)(p1 + 2);
      n12 = *(const f32x2*)(p1 + 4); n13 = *(const f32x2*)(p1 + 6);
    }
    bf16x8 a0 = pack8(c00, c01, c02, c03);
    bf16x8 a1 = pack8(c10, c11, c12, c13);
#pragma unroll
    for (int ct = 0; ct < 4; ++ct) {
      bf16x8 bb = *(const bf16x8*)(wb + (size_t)(ct * 19 + ks) * 512);
      acc[0][ct] = __builtin_amdgcn_mfma_f32_16x16x32_bf16(a0, bb, acc[0][ct], 0, 0, 0);
      acc[1][ct] = __builtin_amdgcn_mfma_f32_16x16x32_bf16(a1, bb, acc[1][ct], 0, 0, 0);
    }
  }
  // tail ks=18: k = 576 + lg*8 + i  (valid while < 602)
  {
    const float* p0 = xr0 + 576;
    const float* p1 = xr1 + 576;
    bf16x8 a0, a1;
#pragma unroll
    for (int i = 0; i < 8; ++i) {
      bool ok = (576 + lg * 8 + i) < FIN;
      a0[i] = ok ? f2bf(p0[i]) : (short)0;
      a1[i] = ok ? f2bf(p1[i]) : (short)0;
    }
#pragma unroll
    for (int ct = 0; ct < 4; ++ct) {
      bf16x8 bb = *(const bf16x8*)(wb + (size_t)(ct * 19 + 18) * 512);
      acc[0][ct] = __builtin_amdgcn_mfma_f32_16x16x32_bf16(a0, bb, acc[0][ct], 0, 0, 0);
      acc[1][ct] = __builtin_amdgcn_mfma_f32_16x16x32_bf16(a1, bb, acc[1][ct], 0, 0, 0);
    }
  }
#pragma unroll
  for (int rt = 0; rt < 2; ++rt)
#pragma unroll
    for (int ct = 0; ct < 4; ++ct)
#pragma unroll
      for (int j = 0; j < 4; ++j) {
        int row = row0 + rt * 16 + lg * 4 + j;
        int col = w * 64 + ct * 16 + lr;
        t1[(size_t)row * HID + col] = f2bf(acc[rt][ct][j]);
      }
}

// ---------------- gather1: hag[n] = mean(t1[neighbors]) + bl1 (bf16) ----------------
__global__ __launch_bounds__(256) void k_gather1(const short* __restrict__ t1, const int* __restrict__ rowptr,
                                                 const int* __restrict__ esorted, const float* __restrict__ bl,
                                                 short* __restrict__ hag) {
  int t = blockIdx.x * 256 + threadIdx.x;
  int n = t >> 6, lane = t & 63;
  if (n >= NN) return;
  int beg = rowptr[n], end = rowptr[n + 1];
  float a0 = 0.f, a1 = 0.f, a2 = 0.f, a3 = 0.f;
  for (int j = beg; j < end; ++j) {
    int s = esorted[j];
    s16x4 v = *(const s16x4*)(t1 + (size_t)s * HID + lane * 4);
    a0 += bf2f(v[0]); a1 += bf2f(v[1]); a2 += bf2f(v[2]); a3 += bf2f(v[3]);
  }
  int deg = end - beg;
  float inv = 1.0f / (float)(deg > 1 ? deg : 1);
  f32x4 b = *(const f32x4*)(bl + lane * 4);
  s16x4 o;
  o[0] = f2bf(a0 * inv + b[0]);
  o[1] = f2bf(a1 * inv + b[1]);
  o[2] = f2bf(a2 * inv + b[2]);
  o[3] = f2bf(a3 * inv + b[3]);
  *(s16x4*)(hag + (size_t)n * HID + lane * 4) = o;
}

// ---- pass 1 fused: h = relu(x@Wr1 + hag) (LDS), then u = h @ [Wl2|Wr2] ----
__global__ __launch_bounds__(256) void k_gemm_l1b(const float* __restrict__ x, const short* __restrict__ wf,
                                                  const short* __restrict__ hag, const short* __restrict__ wf2,
                                                  float* __restrict__ u) {
  __shared__ __align__(16) short hsm[32][264];  // stride 528B: 2-way (free) bank pattern for b128
  const int lane = threadIdx.x & 63;
  const int w = threadIdx.x >> 6;
  const int lr = lane & 15, lg = lane >> 4;
  const int row0 = blockIdx.x * 32;

  f32x4 acc[2][4];
#pragma unroll
  for (int a = 0; a < 2; ++a)
#pragma unroll
    for (int b = 0; b < 4; ++b)
      acc[a][b] = (f32x4){0.f, 0.f, 0.f, 0.f};

  const float* xr0 = x + (size_t)(row0 + lr) * FIN + lg * 8;
  const float* xr1 = xr0 + (size_t)16 * FIN;
  const short* wb = wf + (size_t)(16 + w * 4) * 19 * 512 + lane * 8;  // Wr half

  f32x2 n00 = *(const f32x2*)(xr0 + 0), n01 = *(const f32x2*)(xr0 + 2);
  f32x2 n02 = *(const f32x2*)(xr0 + 4), n03 = *(const f32x2*)(xr0 + 6);
  f32x2 n10 = *(const f32x2*)(xr1 + 0), n11 = *(const f32x2*)(xr1 + 2);
  f32x2 n12 = *(const f32x2*)(xr1 + 4), n13 = *(const f32x2*)(xr1 + 6);

#pragma unroll
  for (int ks = 0; ks < 18; ++ks) {
    f32x2 c00 = n00, c01 = n01, c02 = n02, c03 = n03;
    f32x2 c10 = n10, c11 = n11, c12 = n12, c13 = n13;
    if (ks < 17) {
      const float* p0 = xr0 + (ks + 1) * 32;
      const float* p1 = xr1 + (ks + 1) * 32;
      n00 = *(const f32x2*)(p0 + 0); n01 = *(const f32x2*)(p0 + 2);
      n02 = *(const f32x2*)(p0 + 4); n03 = *(const f32x2*)(p0 + 6);
      n10 = *(const f32x2*)(p1 + 0); n11 = *(const f32x2*)(p1 + 2);
      n12 = *(const f32x2*)(p1 + 4); n13 = *(const f32x2*)(p1 + 6);
    }
    bf16x8 a0 = pack8(c00, c01, c02, c03);
    bf16x8 a1 = pack8(c10, c11, c12, c13);
#pragma unroll
    for (int ct = 0; ct < 4; ++ct) {
      bf16x8 bb = *(const bf16x8*)(wb + (size_t)(ct * 19 + ks) * 512);
      acc[0][ct] = __builtin_amdgcn_mfma_f32_16x16x32_bf16(a0, bb, acc[0][ct], 0, 0, 0);
      acc[1][ct] = __builtin_amdgcn_mfma_f32_16x16x32_bf16(a1, bb, acc[1][ct], 0, 0, 0);
    }
  }
  {
    const float* p0 = xr0 + 576;
    const float* p1 = xr1 + 576;
    bf16x8 a0, a1;
#pragma unroll
    for (int i = 0; i < 8; ++i) {
      bool ok = (576 + lg * 8 + i) < FIN;
      a0[i] = ok ? f2bf(p0[i]) : (short)0;
      a1[i] = ok ? f2bf(p1[i]) : (short)0;
    }
#pragma unroll
    for (int ct = 0; ct < 4; ++ct) {
      bf16x8 bb = *(const bf16x8*)(wb + (size_t)(ct * 19 + 18) * 512);
      acc[0][ct] = __builtin_amdgcn_mfma_f32_16x16x32_bf16(a0, bb, acc[0][ct], 0, 0, 0);
      acc[1][ct] = __builtin_amdgcn_mfma_f32_16x16x32_bf16(a1, bb, acc[1][ct], 0, 0, 0);
    }
  }
  // phase 1: raw acc -> LDS (bf16)
#pragma unroll
  for (int rt = 0; rt < 2; ++rt)
#pragma unroll
    for (int ct = 0; ct < 4; ++ct)
#pragma unroll
      for (int j = 0; j < 4; ++j)
        hsm[rt * 16 + lg * 4 + j][w * 64 + ct * 16 + lr] = f2bf(acc[rt][ct][j]);
  __syncthreads();
  // phase 2: h = relu(acc + hag), coalesced hag reads; write back to LDS
  {
    int tr = threadIdx.x >> 3;         // 0..31
    int tc = (threadIdx.x & 7) * 32;   // 0..224
    int n = row0 + tr;
#pragma unroll
    for (int q = 0; q < 4; ++q) {
      bf16x8 hv = *(const bf16x8*)(hag + (size_t)n * HID + tc + q * 8);
      bf16x8 av = *(const bf16x8*)(&hsm[tr][tc + q * 8]);
      bf16x8 o;
#pragma unroll
      for (int i = 0; i < 8; ++i) {
        float v = bf2f(av[i]) + bf2f(hv[i]);
        o[i] = f2bf(v > 0.f ? v : 0.f);
      }
      *(bf16x8*)(&hsm[tr][tc + q * 8]) = o;
    }
  }
  __syncthreads();
  // phase 3: u[32,96] = h[32,256] @ wf2 ; wave w: rows (w>>1)*16.., ct tiles (w&1)*3..+2
  {
    const int rf = w >> 1;
    const int cb = (w & 1) * 3;
    f32x4 acc2[3];
#pragma unroll
    for (int c = 0; c < 3; ++c) acc2[c] = (f32x4){0.f, 0.f, 0.f, 0.f};
#pragma unroll
    for (int ks = 0; ks < 8; ++ks) {
      bf16x8 af = *(const bf16x8*)(&hsm[rf * 16 + lr][ks * 32 + lg * 8]);
#pragma unroll
      for (int c = 0; c < 3; ++c) {
        bf16x8 bb = *(const bf16x8*)(wf2 + (size_t)((cb + c) * 8 + ks) * 512 + lane * 8);
        acc2[c] = __builtin_amdgcn_mfma_f32_16x16x32_bf16(af, bb, acc2[c], 0, 0, 0);
      }
    }
#pragma unroll
    for (int c = 0; c < 3; ++c)
#pragma unroll
      for (int j = 0; j < 4; ++j) {
        int row = row0 + rf * 16 + lg * 4 + j;
        int col = (cb + c) * 16 + lr;
        u[(size_t)row * 96 + col] = acc2[c][j];
      }
  }
}

// ---------------- final: log_softmax(mean(u[nbrs,0:42]) + bl2 + u[:,42:84]) ----------------
__global__ __launch_bounds__(256) void k_final(const float* __restrict__ u, const int* __restrict__ rowptr,
                                               const int* __restrict__ esorted, const float* __restrict__ bl,
                                               float* __restrict__ out) {
  int t = blockIdx.x * 256 + threadIdx.x;
  int n = t >> 6, c = t & 63;
  if (n >= NN) return;
  int beg = rowptr[n], end = rowptr[n + 1];
  float a = 0.f;
  if (c < NC) {
    for (int j = beg; j < end; ++j) {
      int s = esorted[j];
      a += u[(size_t)s * 96 + c];
    }
  }
  int deg = end - beg;
  float inv = 1.0f / (float)(deg > 1 ? deg : 1);
  float v = (c < NC) ? (a * inv + bl[c] + u[(size_t)n * 96 + NC + c]) : -1e30f;
  float m = v;
#pragma unroll
  for (int off = 32; off > 0; off >>= 1) m = fmaxf(m, __shfl_xor(m, off));
  float e = (c < NC) ? __expf(v - m) : 0.f;
#pragma unroll
  for (int off = 32; off > 0; off >>= 1) e += __shfl_xor(e, off);
  float lse = __logf(e);
  if (c < NC) out[(size_t)n * NC + c] = v - m - lse;
}

extern "C" void kernel_launch(void* const* d_in, const int* in_sizes, int n_in,
                              void* d_out, int out_size, void* d_ws, size_t ws_size,
                              hipStream_t stream) {
  const float* x   = (const float*)d_in[0];
  const int* eidx  = (const int*)d_in[1];
  const float* Wl1 = (const float*)d_in[2];
  const float* bl1 = (const float*)d_in[3];
  const float* Wr1 = (const float*)d_in[4];
  const float* Wl2 = (const float*)d_in[5];
  const float* bl2 = (const float*)d_in[6];
  const float* Wr2 = (const float*)d_in[7];
  float* out = (float*)d_out;
  const int* src = eidx;
  const int* dstp = eidx + NE;

  // workspace layout (bytes) — peak 102.83 MiB (same as validated round 1)
  char* ws = (char*)d_ws;
  int*   cnt     = (int*)(ws + 0);           //   400,000
  int*   rowptr  = (int*)(ws + 524288);      //   400,004
  int*   epos    = (int*)(ws + 1048576);     //   400,000
  int*   bsum    = (int*)(ws + 1462272);     //       392
  short* wf1     = (short*)(ws + 1572864);   //   622,592
  short* wf2     = (short*)(ws + 2359296);   //    49,152
  int*   esorted = (int*)(ws + 2621440);     // 1,600,000  (ends 4,221,440)
  short* t1      = (short*)(ws + 5242880);   // 51,200,000 (ends 56,442,880)
  short* hag     = (short*)(ws + 56623104);  // 51,200,000 (ends 107,823,104)
  float* u       = (float*)(ws + 5242880);   // 38,400,000 — t1 dead after gather1

  hipMemsetAsync(cnt, 0, (size_t)NN * sizeof(int), stream);
  hipMemsetAsync(epos, 0, (size_t)NN * sizeof(int), stream);
  k_prep_w1<<<(32 * 19 * 512 + 255) / 256, 256, 0, stream>>>(Wl1, Wr1, wf1);
  k_prep_w2<<<(6 * 8 * 512 + 255) / 256, 256, 0, stream>>>(Wl2, Wr2, wf2);
  k_count<<<(NE + 255) / 256, 256, 0, stream>>>(dstp, cnt);
  k_scan_local<<<NB_SCAN, 1024, 0, stream>>>(cnt, rowptr, bsum);
  k_scan_bsum<<<1, 128, 0, stream>>>(bsum);
  k_scan_add<<<NB_SCAN, 1024, 0, stream>>>(rowptr, bsum);
  k_sort<<<(NE + 255) / 256, 256, 0, stream>>>(src, dstp, rowptr, epos, esorted);
  k_gemm_l1a<<<NN / 32, 256, 0, stream>>>(x, wf1, t1);
  k_gather1<<<(NN * 64) / 256, 256, 0, stream>>>(t1, rowptr, esorted, bl1, hag);
  k_gemm_l1b<<<NN / 32, 256, 0, stream>>>(x, wf1, hag, wf2, u);
  k_final<<<(NN * 64) / 256, 256, 0, stream>>>(u, rowptr, esorted, bl2, out);
}

// Round 5
// 776.017 us; speedup vs baseline: 1.0723x; 1.0537x over previous
//
#include <hip/hip_runtime.h>
#include <stdint.h>

#define NN 100000
#define NE 400000
#define FIN 602
#define HID 256
#define NC 42
#define NB_SCAN 98   // ceil(NN/1024)

typedef __attribute__((ext_vector_type(8))) short bf16x8;
typedef __attribute__((ext_vector_type(4))) float f32x4;
typedef __attribute__((ext_vector_type(2))) float f32x2;
typedef __attribute__((ext_vector_type(4))) short s16x4;

static __device__ __forceinline__ short f2bf(float f) {
  union { float f; uint32_t u; } v; v.f = f;
  uint32_t r = (v.u + 0x7fffu + ((v.u >> 16) & 1u)) >> 16;
  return (short)(uint16_t)r;
}
static __device__ __forceinline__ float bf2f(short s) {
  union { uint32_t u; float f; } v; v.u = ((uint32_t)(uint16_t)s) << 16;
  return v.f;
}
// HW packed f32->bf16 (RNE)
static __device__ __forceinline__ uint32_t cvtpk(float a, float b) {
  uint32_t r;
  asm("v_cvt_pk_bf16_f32 %0, %1, %2" : "=v"(r) : "v"(a), "v"(b));
  return r;
}
static __device__ __forceinline__ bf16x8 pack8(f32x2 a, f32x2 b, f32x2 c, f32x2 d) {
  union { bf16x8 v; uint32_t u[4]; } r;
  r.u[0] = cvtpk(a[0], a[1]);
  r.u[1] = cvtpk(b[0], b[1]);
  r.u[2] = cvtpk(c[0], c[1]);
  r.u[3] = cvtpk(d[0], d[1]);
  return r.v;
}

// ---------------- degree count ----------------
__global__ __launch_bounds__(256) void k_count(const int* __restrict__ dst, int* __restrict__ cnt) {
  int t = blockIdx.x * 256 + threadIdx.x;
  if (t < NE) atomicAdd(&cnt[dst[t]], 1);
}

// ---------------- scan: rowptr = exclusive prefix of cnt ----------------
__global__ __launch_bounds__(1024) void k_scan_local(const int* __restrict__ cnt, int* __restrict__ rowptr,
                                                     int* __restrict__ bsum) {
  __shared__ int sm[1024];
  int tid = threadIdx.x, t = blockIdx.x * 1024 + tid;
  int v = (t < NN) ? cnt[t] : 0;
  sm[tid] = v;
  __syncthreads();
  for (int off = 1; off < 1024; off <<= 1) {
    int y = (tid >= off) ? sm[tid - off] : 0;
    __syncthreads();
    sm[tid] += y;
    __syncthreads();
  }
  if (t < NN) rowptr[t] = sm[tid] - v;  // local exclusive
  if (tid == 1023) bsum[blockIdx.x] = sm[tid];
}
__global__ __launch_bounds__(128) void k_scan_bsum(int* __restrict__ bsum) {
  __shared__ int sm[128];
  int tid = threadIdx.x;
  int v = (tid < NB_SCAN) ? bsum[tid] : 0;
  sm[tid] = v;
  __syncthreads();
  for (int off = 1; off < 128; off <<= 1) {
    int y = (tid >= off) ? sm[tid - off] : 0;
    __syncthreads();
    sm[tid] += y;
    __syncthreads();
  }
  if (tid < NB_SCAN) bsum[tid] = sm[tid] - v;  // exclusive
}
__global__ __launch_bounds__(1024) void k_scan_add(int* __restrict__ rowptr, const int* __restrict__ bsum) {
  int t = blockIdx.x * 1024 + threadIdx.x;
  if (t < NN) rowptr[t] += bsum[t >> 10];
  if (t == 0) rowptr[NN] = NE;
}

// ---------------- bucket sort edges by dst: esorted[j] = src ----------------
__global__ __launch_bounds__(256) void k_sort(const int* __restrict__ src, const int* __restrict__ dst,
                                              const int* __restrict__ rowptr, int* __restrict__ epos,
                                              int* __restrict__ esorted) {
  int t = blockIdx.x * 256 + threadIdx.x;
  if (t >= NE) return;
  int d = dst[t];
  int p = atomicAdd(&epos[d], 1);
  esorted[rowptr[d] + p] = src[t];
}

// ------------- weight prep: fragment-ordered bf16 -------------
// wf[(((ct*19)+ks)*64 + lane)*8 + i] = W[k = ks*32 + (lane>>4)*8 + i][c = ct*16 + (lane&15)]
// ct in [0,16): Wl (cols 0..255); ct in [16,32): Wr (cols 256..511)
__global__ __launch_bounds__(256) void k_prep_w1(const float* __restrict__ Wl, const float* __restrict__ Wr,
                                                 short* __restrict__ wf) {
  int idx = blockIdx.x * 256 + threadIdx.x;
  if (idx >= 32 * 19 * 512) return;
  int i = idx & 7, l = (idx >> 3) & 63, rest = idx >> 9;
  int ks = rest % 19, ct = rest / 19;
  int c = ct * 16 + (l & 15);
  int k = ks * 32 + ((l >> 4) << 3) + i;
  float v = 0.f;
  if (k < FIN) v = (c < HID) ? Wl[k * HID + c] : Wr[k * HID + (c - HID)];
  wf[idx] = f2bf(v);
}
__global__ __launch_bounds__(256) void k_prep_w2(const float* __restrict__ Wl, const float* __restrict__ Wr,
                                                 short* __restrict__ wf) {
  int idx = blockIdx.x * 256 + threadIdx.x;
  if (idx >= 6 * 8 * 512) return;
  int i = idx & 7, l = (idx >> 3) & 63, rest = idx >> 9;
  int ks = rest & 7, ct = rest >> 3;
  int c = ct * 16 + (l & 15);
  int k = ks * 32 + ((l >> 4) << 3) + i;
  float v = 0.f;
  if (c < NC) v = Wl[k * NC + c];
  else if (c < 2 * NC) v = Wr[k * NC + (c - NC)];
  wf[idx] = f2bf(v);
}

// -------- fused layer-1 GEMM: t1 = bf16(x@Wl1), t2 = bf16(x@Wr1), ONE x pass --------
// 4 waves; BM=32 rows; wave w: Wl tiles [w*4,w*4+4) AND Wr tiles [16+w*4,16+w*4+4)
// FIFO-correct issue order: bb(ks) issued BEFORE x(ks+1), so the MFMA wait on bb(ks)
// does not drain the x prefetch, and the x(ks) wait drains only 1-iter-old loads.
__global__ __launch_bounds__(256) void k_gemm_l1(const float* __restrict__ x, const short* __restrict__ wf,
                                                 short* __restrict__ t1, short* __restrict__ t2) {
  const int lane = threadIdx.x & 63;
  const int w = threadIdx.x >> 6;
  const int lr = lane & 15, lg = lane >> 4;
  const int row0 = blockIdx.x * 32;

  f32x4 acc[2][8];  // [row-tile][0..3: Wl ct, 4..7: Wr ct]
#pragma unroll
  for (int a = 0; a < 2; ++a)
#pragma unroll
    for (int b = 0; b < 8; ++b)
      acc[a][b] = (f32x4){0.f, 0.f, 0.f, 0.f};

  const float* xr0 = x + (size_t)(row0 + lr) * FIN + lg * 8;
  const float* xr1 = xr0 + (size_t)16 * FIN;
  const short* wbL = wf + (size_t)(w * 4) * 19 * 512 + lane * 8;
  const short* wbR = wf + (size_t)(16 + w * 4) * 19 * 512 + lane * 8;

  f32x2 xb[2][8];
  // prologue: x(0)
#pragma unroll
  for (int i = 0; i < 4; ++i) {
    xb[0][i]     = *(const f32x2*)(xr0 + 2 * i);
    xb[0][4 + i] = *(const f32x2*)(xr1 + 2 * i);
  }

#pragma unroll
  for (int ks = 0; ks < 18; ++ks) {
    const int cur = ks & 1, nxt = cur ^ 1;
    // (1) weight loads for THIS iteration (issued before the x prefetch)
    bf16x8 bbL[4], bbR[4];
#pragma unroll
    for (int c = 0; c < 4; ++c) bbL[c] = *(const bf16x8*)(wbL + (size_t)(c * 19 + ks) * 512);
#pragma unroll
    for (int c = 0; c < 4; ++c) bbR[c] = *(const bf16x8*)(wbR + (size_t)(c * 19 + ks) * 512);
    // (2) x prefetch for NEXT iteration
    if (ks < 17) {
      const float* p0 = xr0 + (ks + 1) * 32;
      const float* p1 = xr1 + (ks + 1) * 32;
#pragma unroll
      for (int i = 0; i < 4; ++i) {
        xb[nxt][i]     = *(const f32x2*)(p0 + 2 * i);
        xb[nxt][4 + i] = *(const f32x2*)(p1 + 2 * i);
      }
    }
    // (3) convert + 16 MFMAs
    bf16x8 a0 = pack8(xb[cur][0], xb[cur][1], xb[cur][2], xb[cur][3]);
    bf16x8 a1 = pack8(xb[cur][4], xb[cur][5], xb[cur][6], xb[cur][7]);
#pragma unroll
    for (int c = 0; c < 4; ++c) {
      acc[0][c]     = __builtin_amdgcn_mfma_f32_16x16x32_bf16(a0, bbL[c], acc[0][c], 0, 0, 0);
      acc[1][c]     = __builtin_amdgcn_mfma_f32_16x16x32_bf16(a1, bbL[c], acc[1][c], 0, 0, 0);
      acc[0][4 + c] = __builtin_amdgcn_mfma_f32_16x16x32_bf16(a0, bbR[c], acc[0][4 + c], 0, 0, 0);
      acc[1][4 + c] = __builtin_amdgcn_mfma_f32_16x16x32_bf16(a1, bbR[c], acc[1][4 + c], 0, 0, 0);
    }
  }
  // tail ks=18: k = 576 + lg*8 + i (valid while < 602)
  {
    const float* p0 = xr0 + 576;
    const float* p1 = xr1 + 576;
    bf16x8 a0, a1;
#pragma unroll
    for (int i = 0; i < 8; ++i) {
      bool ok = (576 + lg * 8 + i) < FIN;
      a0[i] = ok ? f2bf(p0[i]) : (short)0;
      a1[i] = ok ? f2bf(p1[i]) : (short)0;
    }
#pragma unroll
    for (int c = 0; c < 4; ++c) {
      bf16x8 bL = *(const bf16x8*)(wbL + (size_t)(c * 19 + 18) * 512);
      bf16x8 bR = *(const bf16x8*)(wbR + (size_t)(c * 19 + 18) * 512);
      acc[0][c]     = __builtin_amdgcn_mfma_f32_16x16x32_bf16(a0, bL, acc[0][c], 0, 0, 0);
      acc[1][c]     = __builtin_amdgcn_mfma_f32_16x16x32_bf16(a1, bL, acc[1][c], 0, 0, 0);
      acc[0][4 + c] = __builtin_amdgcn_mfma_f32_16x16x32_bf16(a0, bR, acc[0][4 + c], 0, 0, 0);
      acc[1][4 + c] = __builtin_amdgcn_mfma_f32_16x16x32_bf16(a1, bR, acc[1][4 + c], 0, 0, 0);
    }
  }
  // store: ct<4 -> t1, ct>=4 -> t2 (same col block w*64)
#pragma unroll
  for (int rt = 0; rt < 2; ++rt)
#pragma unroll
    for (int c = 0; c < 4; ++c)
#pragma unroll
      for (int j = 0; j < 4; ++j) {
        int row = row0 + rt * 16 + lg * 4 + j;
        int col = w * 64 + c * 16 + lr;
        t1[(size_t)row * HID + col] = f2bf(acc[rt][c][j]);
        t2[(size_t)row * HID + col] = f2bf(acc[rt][4 + c][j]);
      }
}

// ---- gather1 (fused combine): h = relu(mean(t1[nbrs]) + bl1 + t2[n]), IN-PLACE over t2 ----
__global__ __launch_bounds__(256) void k_gather1(const short* __restrict__ t1, short* __restrict__ t2h,
                                                 const int* __restrict__ rowptr, const int* __restrict__ esorted,
                                                 const float* __restrict__ bl) {
  int t = blockIdx.x * 256 + threadIdx.x;
  int n = t >> 6, lane = t & 63;
  if (n >= NN) return;
  s16x4 tv = *(const s16x4*)(t2h + (size_t)n * HID + lane * 4);  // own row, read before write
  int beg = rowptr[n], end = rowptr[n + 1];
  float a0 = 0.f, a1 = 0.f, a2 = 0.f, a3 = 0.f;
  for (int j = beg; j < end; ++j) {
    int s = esorted[j];
    s16x4 v = *(const s16x4*)(t1 + (size_t)s * HID + lane * 4);
    a0 += bf2f(v[0]); a1 += bf2f(v[1]); a2 += bf2f(v[2]); a3 += bf2f(v[3]);
  }
  int deg = end - beg;
  float inv = 1.0f / (float)(deg > 1 ? deg : 1);
  f32x4 b = *(const f32x4*)(bl + lane * 4);
  s16x4 o;
  float v0 = a0 * inv + b[0] + bf2f(tv[0]);
  float v1 = a1 * inv + b[1] + bf2f(tv[1]);
  float v2 = a2 * inv + b[2] + bf2f(tv[2]);
  float v3 = a3 * inv + b[3] + bf2f(tv[3]);
  o[0] = f2bf(v0 > 0.f ? v0 : 0.f);
  o[1] = f2bf(v1 > 0.f ? v1 : 0.f);
  o[2] = f2bf(v2 > 0.f ? v2 : 0.f);
  o[3] = f2bf(v3 > 0.f ? v3 : 0.f);
  *(s16x4*)(t2h + (size_t)n * HID + lane * 4) = o;
}

// ---------------- GEMM2: u[N,96] = h[N,256] @ [Wl2|Wr2] (cols 84..95 pad) ----------------
__global__ __launch_bounds__(256) void k_gemm2(const short* __restrict__ h, const short* __restrict__ wf,
                                               float* __restrict__ u) {
  const int lane = threadIdx.x & 63;
  const int w = threadIdx.x >> 6;
  const int lr = lane & 15, lg = lane >> 4;
  const int row0 = blockIdx.x * 128 + w * 32;

  f32x4 acc[2][6];
#pragma unroll
  for (int a = 0; a < 2; ++a)
#pragma unroll
    for (int b = 0; b < 6; ++b)
      acc[a][b] = (f32x4){0.f, 0.f, 0.f, 0.f};

  const int r0 = row0 + lr, r1 = row0 + 16 + lr;
#pragma unroll
  for (int ks = 0; ks < 8; ++ks) {
    bf16x8 a0, a1;
#pragma unroll
    for (int i = 0; i < 8; ++i) { a0[i] = 0; a1[i] = 0; }
    if (r0 < NN) a0 = *(const bf16x8*)(h + (size_t)r0 * HID + ks * 32 + lg * 8);
    if (r1 < NN) a1 = *(const bf16x8*)(h + (size_t)r1 * HID + ks * 32 + lg * 8);
    bf16x8 bfrag[6];
#pragma unroll
    for (int ct = 0; ct < 6; ++ct)
      bfrag[ct] = *(const bf16x8*)(wf + (size_t)((ct * 8 + ks) * 64 + lane) * 8);
#pragma unroll
    for (int ct = 0; ct < 6; ++ct) {
      acc[0][ct] = __builtin_amdgcn_mfma_f32_16x16x32_bf16(a0, bfrag[ct], acc[0][ct], 0, 0, 0);
      acc[1][ct] = __builtin_amdgcn_mfma_f32_16x16x32_bf16(a1, bfrag[ct], acc[1][ct], 0, 0, 0);
    }
  }
#pragma unroll
  for (int rt = 0; rt < 2; ++rt)
#pragma unroll
    for (int ct = 0; ct < 6; ++ct)
#pragma unroll
      for (int j = 0; j < 4; ++j) {
        int row = row0 + rt * 16 + lg * 4 + j;
        int col = ct * 16 + lr;
        if (row < NN) u[(size_t)row * 96 + col] = acc[rt][ct][j];
      }
}

// ---------------- final: log_softmax(mean(u[nbrs,0:42]) + bl2 + u[:,42:84]) ----------------
__global__ __launch_bounds__(256) void k_final(const float* __restrict__ u, const int* __restrict__ rowptr,
                                               const int* __restrict__ esorted, const float* __restrict__ bl,
                                               float* __restrict__ out) {
  int t = blockIdx.x * 256 + threadIdx.x;
  int n = t >> 6, c = t & 63;
  if (n >= NN) return;
  int beg = rowptr[n], end = rowptr[n + 1];
  float a = 0.f;
  if (c < NC) {
    for (int j = beg; j < end; ++j) {
      int s = esorted[j];
      a += u[(size_t)s * 96 + c];
    }
  }
  int deg = end - beg;
  float inv = 1.0f / (float)(deg > 1 ? deg : 1);
  float v = (c < NC) ? (a * inv + bl[c] + u[(size_t)n * 96 + NC + c]) : -1e30f;
  float m = v;
#pragma unroll
  for (int off = 32; off > 0; off >>= 1) m = fmaxf(m, __shfl_xor(m, off));
  float e = (c < NC) ? __expf(v - m) : 0.f;
#pragma unroll
  for (int off = 32; off > 0; off >>= 1) e += __shfl_xor(e, off);
  float lse = __logf(e);
  if (c < NC) out[(size_t)n * NC + c] = v - m - lse;
}

extern "C" void kernel_launch(void* const* d_in, const int* in_sizes, int n_in,
                              void* d_out, int out_size, void* d_ws, size_t ws_size,
                              hipStream_t stream) {
  const float* x   = (const float*)d_in[0];
  const int* eidx  = (const int*)d_in[1];
  const float* Wl1 = (const float*)d_in[2];
  const float* bl1 = (const float*)d_in[3];
  const float* Wr1 = (const float*)d_in[4];
  const float* Wl2 = (const float*)d_in[5];
  const float* bl2 = (const float*)d_in[6];
  const float* Wr2 = (const float*)d_in[7];
  float* out = (float*)d_out;
  const int* src = eidx;
  const int* dstp = eidx + NE;

  // workspace layout (bytes) — peak 106,700,800 B < proven 107,823,104 B footprint
  char* ws = (char*)d_ws;
  int*   cnt     = (int*)(ws + 0);            //   400,000
  int*   rowptr  = (int*)(ws + 524288);       //   400,004
  int*   epos    = (int*)(ws + 1048576);      //   400,000
  int*   bsum    = (int*)(ws + 1462272);      //       392
  short* wf1     = (short*)(ws + 1572864);    //   622,592
  short* wf2     = (short*)(ws + 2359296);    //    49,152
  int*   esorted = (int*)(ws + 2621440);      // 1,600,000  (ends 4,221,440)
  short* t1      = (short*)(ws + 4300800);    // 51,200,000 (ends 55,500,800)
  short* t2h     = (short*)(ws + 55500800);   // 51,200,000 (ends 106,700,800); becomes h in-place
  float* u       = (float*)(ws + 4300800);    // 38,400,000 — t1 dead after gather1

  hipMemsetAsync(cnt, 0, (size_t)NN * sizeof(int), stream);
  hipMemsetAsync(epos, 0, (size_t)NN * sizeof(int), stream);
  k_prep_w1<<<(32 * 19 * 512 + 255) / 256, 256, 0, stream>>>(Wl1, Wr1, wf1);
  k_prep_w2<<<(6 * 8 * 512 + 255) / 256, 256, 0, stream>>>(Wl2, Wr2, wf2);
  k_count<<<(NE + 255) / 256, 256, 0, stream>>>(dstp, cnt);
  k_scan_local<<<NB_SCAN, 1024, 0, stream>>>(cnt, rowptr, bsum);
  k_scan_bsum<<<1, 128, 0, stream>>>(bsum);
  k_scan_add<<<NB_SCAN, 1024, 0, stream>>>(rowptr, bsum);
  k_sort<<<(NE + 255) / 256, 256, 0, stream>>>(src, dstp, rowptr, epos, esorted);
  k_gemm_l1<<<NN / 32, 256, 0, stream>>>(x, wf1, t1, t2h);
  k_gather1<<<(NN * 64) / 256, 256, 0, stream>>>(t1, t2h, rowptr, esorted, bl1);
  k_gemm2<<<(NN + 127) / 128, 256, 0, stream>>>(t2h, wf2, u);
  k_final<<<(NN * 64) / 256, 256, 0, stream>>>(u, rowptr, esorted, bl2, out);
}

// Round 7
// 708.186 us; speedup vs baseline: 1.1750x; 1.0958x over previous
//
#include <hip/hip_runtime.h>
#include <stdint.h>

#define NN 100000
#define NE 400000
#define FIN 602
#define HID 256
#define NC 42
#define NB_SCAN 98   // ceil(NN/1024)

typedef __attribute__((ext_vector_type(8))) short bf16x8;
typedef __attribute__((ext_vector_type(4))) float f32x4;
typedef __attribute__((ext_vector_type(2))) float f32x2;
typedef __attribute__((ext_vector_type(4))) short s16x4;

static __device__ __forceinline__ short f2bf(float f) {
  union { float f; uint32_t u; } v; v.f = f;
  uint32_t r = (v.u + 0x7fffu + ((v.u >> 16) & 1u)) >> 16;
  return (short)(uint16_t)r;
}
static __device__ __forceinline__ float bf2f(short s) {
  union { uint32_t u; float f; } v; v.u = ((uint32_t)(uint16_t)s) << 16;
  return v.f;
}
// HW packed f32->bf16 (RNE)
static __device__ __forceinline__ uint32_t cvtpk(float a, float b) {
  uint32_t r;
  asm("v_cvt_pk_bf16_f32 %0, %1, %2" : "=v"(r) : "v"(a), "v"(b));
  return r;
}
static __device__ __forceinline__ bf16x8 pack8q(f32x4 a, f32x4 b) {
  union { bf16x8 v; uint32_t u[4]; } r;
  r.u[0] = cvtpk(a[0], a[1]);
  r.u[1] = cvtpk(a[2], a[3]);
  r.u[2] = cvtpk(b[0], b[1]);
  r.u[3] = cvtpk(b[2], b[3]);
  return r.v;
}
// async global->LDS, 4 bytes per lane, LDS dest = ldsbase + lane*4 (wave-uniform base)
static __device__ __forceinline__ void gload_lds4(const float* g, float* lds) {
  __builtin_amdgcn_global_load_lds((const __attribute__((address_space(1))) void*)g,
                                   (__attribute__((address_space(3))) void*)lds, 4, 0, 0);
}

// ---------------- degree count ----------------
__global__ __launch_bounds__(256) void k_count(const int* __restrict__ dst, int* __restrict__ cnt) {
  int t = blockIdx.x * 256 + threadIdx.x;
  if (t < NE) atomicAdd(&cnt[dst[t]], 1);
}

// ---------------- scan: rowptr = exclusive prefix of cnt ----------------
__global__ __launch_bounds__(1024) void k_scan_local(const int* __restrict__ cnt, int* __restrict__ rowptr,
                                                     int* __restrict__ bsum) {
  __shared__ int sm[1024];
  int tid = threadIdx.x, t = blockIdx.x * 1024 + tid;
  int v = (t < NN) ? cnt[t] : 0;
  sm[tid] = v;
  __syncthreads();
  for (int off = 1; off < 1024; off <<= 1) {
    int y = (tid >= off) ? sm[tid - off] : 0;
    __syncthreads();
    sm[tid] += y;
    __syncthreads();
  }
  if (t < NN) rowptr[t] = sm[tid] - v;  // local exclusive
  if (tid == 1023) bsum[blockIdx.x] = sm[tid];
}
__global__ __launch_bounds__(128) void k_scan_bsum(int* __restrict__ bsum) {
  __shared__ int sm[128];
  int tid = threadIdx.x;
  int v = (tid < NB_SCAN) ? bsum[tid] : 0;
  sm[tid] = v;
  __syncthreads();
  for (int off = 1; off < 128; off <<= 1) {
    int y = (tid >= off) ? sm[tid - off] : 0;
    __syncthreads();
    sm[tid] += y;
    __syncthreads();
  }
  if (tid < NB_SCAN) bsum[tid] = sm[tid] - v;  // exclusive
}
__global__ __launch_bounds__(1024) void k_scan_add(int* __restrict__ rowptr, const int* __restrict__ bsum) {
  int t = blockIdx.x * 1024 + threadIdx.x;
  if (t < NN) rowptr[t] += bsum[t >> 10];
  if (t == 0) rowptr[NN] = NE;
}

// ---------------- bucket sort edges by dst: esorted[j] = src ----------------
__global__ __launch_bounds__(256) void k_sort(const int* __restrict__ src, const int* __restrict__ dst,
                                              const int* __restrict__ rowptr, int* __restrict__ epos,
                                              int* __restrict__ esorted) {
  int t = blockIdx.x * 256 + threadIdx.x;
  if (t >= NE) return;
  int d = dst[t];
  int p = atomicAdd(&epos[d], 1);
  esorted[rowptr[d] + p] = src[t];
}

// ------------- weight prep: fragment-ordered bf16 -------------
// wf[(((ct*19)+ks)*64 + lane)*8 + i] = W[k = ks*32 + (lane>>4)*8 + i][c = ct*16 + (lane&15)]
// ct in [0,16): Wl (cols 0..255); ct in [16,32): Wr (cols 256..511). k>=602 -> 0.
__global__ __launch_bounds__(256) void k_prep_w1(const float* __restrict__ Wl, const float* __restrict__ Wr,
                                                 short* __restrict__ wf) {
  int idx = blockIdx.x * 256 + threadIdx.x;
  if (idx >= 32 * 19 * 512) return;
  int i = idx & 7, l = (idx >> 3) & 63, rest = idx >> 9;
  int ks = rest % 19, ct = rest / 19;
  int c = ct * 16 + (l & 15);
  int k = ks * 32 + ((l >> 4) << 3) + i;
  float v = 0.f;
  if (k < FIN) v = (c < HID) ? Wl[k * HID + c] : Wr[k * HID + (c - HID)];
  wf[idx] = f2bf(v);
}
__global__ __launch_bounds__(256) void k_prep_w2(const float* __restrict__ Wl, const float* __restrict__ Wr,
                                                 short* __restrict__ wf) {
  int idx = blockIdx.x * 256 + threadIdx.x;
  if (idx >= 6 * 8 * 512) return;
  int i = idx & 7, l = (idx >> 3) & 63, rest = idx >> 9;
  int ks = rest & 7, ct = rest >> 3;
  int c = ct * 16 + (l & 15);
  int k = ks * 32 + ((l >> 4) << 3) + i;
  float v = 0.f;
  if (c < NC) v = Wl[k * NC + c];
  else if (c < 2 * NC) v = Wr[k * NC + (c - NC)];
  wf[idx] = f2bf(v);
}

// -------- fused layer-1 GEMM: t1 = bf16(x@Wl1), t2 = bf16(x@Wr1) --------
// BM=64 rows/block, 4 waves. Wave w: all 64 rows x cols [w*64, w*64+64) of both Wl and Wr.
// x staged via global_load_lds (dword, coalesced 2x128B per instr) into double-buffered LDS.
// XOR swizzle on 16B quads: stage source pre-swizzled (quad ld = pq ^ (r&7)), ds_read applies
// the same XOR -> involution; 8 lanes per 16B slot = structural-optimal bank spread.
__global__ __launch_bounds__(256) void k_gemm_l1(const float* __restrict__ x, const short* __restrict__ wf,
                                                 short* __restrict__ t1, short* __restrict__ t2) {
  __shared__ float xs[2][64 * 32];  // 2 x 8KB
  const int lane = threadIdx.x & 63;
  const int w = threadIdx.x >> 6;
  const int lr = lane & 15, lg = lane >> 4;
  const int row0 = blockIdx.x * 64;

  f32x4 acc[4][8];  // [row-frag][0..3 = Wl ct, 4..7 = Wr ct]
#pragma unroll
  for (int a = 0; a < 4; ++a)
#pragma unroll
    for (int b = 0; b < 8; ++b)
      acc[a][b] = (f32x4){0.f, 0.f, 0.f, 0.f};

  const short* wbL = wf + (size_t)(w * 4) * 19 * 512 + lane * 8;
  const short* wbR = wf + (size_t)(16 + w * 4) * 19 * 512 + lane * 8;

  // staging lane geometry: instr q covers rows (w*16 + 2q) and +1; lane 0..31 -> row A, 32..63 -> row B
  const int s_rhalf = lane >> 5;         // 0/1
  const int s_pq = (lane & 31) >> 2;     // phys quad 0..7
  const int s_pe = lane & 3;             // dword within quad

#define STAGE(KS, BUF)                                                                   \
  {                                                                                      \
    _Pragma("unroll")                                                                    \
    for (int q = 0; q < 8; ++q) {                                                        \
      int r = w * 16 + 2 * q + s_rhalf;                                                  \
      int rs = row0 + r; rs = rs < NN ? rs : NN - 1;                                     \
      int ld = ((s_pq ^ (r & 7)) << 2) | s_pe;                                           \
      int k = (KS) * 32 + ld;                                                            \
      k = k < FIN ? k : 0;                                                               \
      gload_lds4(x + (size_t)rs * FIN + k, &xs[BUF][(w * 16 + 2 * q) * 32]);             \
    }                                                                                    \
  }

  STAGE(0, 0);
  __syncthreads();

  for (int ks = 0; ks < 19; ++ks) {
    const int cur = ks & 1;
    if (ks < 18) STAGE(ks + 1, cur ^ 1);
    // weight fragments for this K-step (L2-resident, coalesced 1KB/instr)
    bf16x8 bbL[4], bbR[4];
#pragma unroll
    for (int c = 0; c < 4; ++c) bbL[c] = *(const bf16x8*)(wbL + (size_t)(c * 19 + ks) * 512);
#pragma unroll
    for (int c = 0; c < 4; ++c) bbR[c] = *(const bf16x8*)(wbR + (size_t)(c * 19 + ks) * 512);
    // A fragments from LDS (swizzled), convert to bf16
    bf16x8 af[4];
#pragma unroll
    for (int t = 0; t < 4; ++t) {
      const char* rowp = (const char*)&xs[cur][(t * 16 + lr) * 32];
      f32x4 v0 = *(const f32x4*)(rowp + (((lg * 2 + 0) ^ (lr & 7)) << 4));
      f32x4 v1 = *(const f32x4*)(rowp + (((lg * 2 + 1) ^ (lr & 7)) << 4));
      af[t] = pack8q(v0, v1);
    }
    // 32 MFMAs
#pragma unroll
    for (int c = 0; c < 4; ++c)
#pragma unroll
      for (int t = 0; t < 4; ++t) {
        acc[t][c]     = __builtin_amdgcn_mfma_f32_16x16x32_bf16(af[t], bbL[c], acc[t][c], 0, 0, 0);
        acc[t][4 + c] = __builtin_amdgcn_mfma_f32_16x16x32_bf16(af[t], bbR[c], acc[t][4 + c], 0, 0, 0);
      }
    __syncthreads();  // full drain: next-tile staging complete + all reads of cur done
  }
#undef STAGE

  // stores: ct<4 -> t1, ct>=4 -> t2 (col block w*64)
#pragma unroll
  for (int t = 0; t < 4; ++t)
#pragma unroll
    for (int c = 0; c < 8; ++c)
#pragma unroll
      for (int j = 0; j < 4; ++j) {
        int row = row0 + t * 16 + lg * 4 + j;
        if (row < NN) {
          int col = w * 64 + (c & 3) * 16 + lr;
          short* dstb = (c < 4) ? t1 : t2;
          dstb[(size_t)row * HID + col] = f2bf(acc[t][c][j]);
        }
      }
}

// ---- gather1 (fused combine): h = relu(mean(t1[nbrs]) + bl1 + t2[n]), IN-PLACE over t2 ----
__global__ __launch_bounds__(256) void k_gather1(const short* __restrict__ t1, short* __restrict__ t2h,
                                                 const int* __restrict__ rowptr, const int* __restrict__ esorted,
                                                 const float* __restrict__ bl) {
  int t = blockIdx.x * 256 + threadIdx.x;
  int n = t >> 6, lane = t & 63;
  if (n >= NN) return;
  s16x4 tv = *(const s16x4*)(t2h + (size_t)n * HID + lane * 4);  // own row, read before write
  int beg = rowptr[n], end = rowptr[n + 1];
  float a0 = 0.f, a1 = 0.f, a2 = 0.f, a3 = 0.f;
  for (int j = beg; j < end; ++j) {
    int s = esorted[j];
    s16x4 v = *(const s16x4*)(t1 + (size_t)s * HID + lane * 4);
    a0 += bf2f(v[0]); a1 += bf2f(v[1]); a2 += bf2f(v[2]); a3 += bf2f(v[3]);
  }
  int deg = end - beg;
  float inv = 1.0f / (float)(deg > 1 ? deg : 1);
  f32x4 b = *(const f32x4*)(bl + lane * 4);
  s16x4 o;
  float v0 = a0 * inv + b[0] + bf2f(tv[0]);
  float v1 = a1 * inv + b[1] + bf2f(tv[1]);
  float v2 = a2 * inv + b[2] + bf2f(tv[2]);
  float v3 = a3 * inv + b[3] + bf2f(tv[3]);
  o[0] = f2bf(v0 > 0.f ? v0 : 0.f);
  o[1] = f2bf(v1 > 0.f ? v1 : 0.f);
  o[2] = f2bf(v2 > 0.f ? v2 : 0.f);
  o[3] = f2bf(v3 > 0.f ? v3 : 0.f);
  *(s16x4*)(t2h + (size_t)n * HID + lane * 4) = o;
}

// ---------------- GEMM2: u[N,96] = h[N,256] @ [Wl2|Wr2] (cols 84..95 pad) ----------------
__global__ __launch_bounds__(256) void k_gemm2(const short* __restrict__ h, const short* __restrict__ wf,
                                               float* __restrict__ u) {
  const int lane = threadIdx.x & 63;
  const int w = threadIdx.x >> 6;
  const int lr = lane & 15, lg = lane >> 4;
  const int row0 = blockIdx.x * 128 + w * 32;

  f32x4 acc[2][6];
#pragma unroll
  for (int a = 0; a < 2; ++a)
#pragma unroll
    for (int b = 0; b < 6; ++b)
      acc[a][b] = (f32x4){0.f, 0.f, 0.f, 0.f};

  const int r0 = row0 + lr, r1 = row0 + 16 + lr;
#pragma unroll
  for (int ks = 0; ks < 8; ++ks) {
    bf16x8 a0, a1;
#pragma unroll
    for (int i = 0; i < 8; ++i) { a0[i] = 0; a1[i] = 0; }
    if (r0 < NN) a0 = *(const bf16x8*)(h + (size_t)r0 * HID + ks * 32 + lg * 8);
    if (r1 < NN) a1 = *(const bf16x8*)(h + (size_t)r1 * HID + ks * 32 + lg * 8);
    bf16x8 bfrag[6];
#pragma unroll
    for (int ct = 0; ct < 6; ++ct)
      bfrag[ct] = *(const bf16x8*)(wf + (size_t)((ct * 8 + ks) * 64 + lane) * 8);
#pragma unroll
    for (int ct = 0; ct < 6; ++ct) {
      acc[0][ct] = __builtin_amdgcn_mfma_f32_16x16x32_bf16(a0, bfrag[ct], acc[0][ct], 0, 0, 0);
      acc[1][ct] = __builtin_amdgcn_mfma_f32_16x16x32_bf16(a1, bfrag[ct], acc[1][ct], 0, 0, 0);
    }
  }
#pragma unroll
  for (int rt = 0; rt < 2; ++rt)
#pragma unroll
    for (int ct = 0; ct < 6; ++ct)
#pragma unroll
      for (int j = 0; j < 4; ++j) {
        int row = row0 + rt * 16 + lg * 4 + j;
        int col = ct * 16 + lr;
        if (row < NN) u[(size_t)row * 96 + col] = acc[rt][ct][j];
      }
}

// ---------------- final: log_softmax(mean(u[nbrs,0:42]) + bl2 + u[:,42:84]) ----------------
__global__ __launch_bounds__(256) void k_final(const float* __restrict__ u, const int* __restrict__ rowptr,
                                               const int* __restrict__ esorted, const float* __restrict__ bl,
                                               float* __restrict__ out) {
  int t = blockIdx.x * 256 + threadIdx.x;
  int n = t >> 6, c = t & 63;
  if (n >= NN) return;
  int beg = rowptr[n], end = rowptr[n + 1];
  float a = 0.f;
  if (c < NC) {
    for (int j = beg; j < end; ++j) {
      int s = esorted[j];
      a += u[(size_t)s * 96 + c];
    }
  }
  int deg = end - beg;
  float inv = 1.0f / (float)(deg > 1 ? deg : 1);
  float v = (c < NC) ? (a * inv + bl[c] + u[(size_t)n * 96 + NC + c]) : -1e30f;
  float m = v;
#pragma unroll
  for (int off = 32; off > 0; off >>= 1) m = fmaxf(m, __shfl_xor(m, off));
  float e = (c < NC) ? __expf(v - m) : 0.f;
#pragma unroll
  for (int off = 32; off > 0; off >>= 1) e += __shfl_xor(e, off);
  float lse = __logf(e);
  if (c < NC) out[(size_t)n * NC + c] = v - m - lse;
}

extern "C" void kernel_launch(void* const* d_in, const int* in_sizes, int n_in,
                              void* d_out, int out_size, void* d_ws, size_t ws_size,
                              hipStream_t stream) {
  const float* x   = (const float*)d_in[0];
  const int* eidx  = (const int*)d_in[1];
  const float* Wl1 = (const float*)d_in[2];
  const float* bl1 = (const float*)d_in[3];
  const float* Wr1 = (const float*)d_in[4];
  const float* Wl2 = (const float*)d_in[5];
  const float* bl2 = (const float*)d_in[6];
  const float* Wr2 = (const float*)d_in[7];
  float* out = (float*)d_out;
  const int* src = eidx;
  const int* dstp = eidx + NE;

  // workspace layout (bytes) — peak 106,700,800 B (validated footprint)
  char* ws = (char*)d_ws;
  int*   cnt     = (int*)(ws + 0);            //   400,000
  int*   rowptr  = (int*)(ws + 524288);       //   400,004
  int*   epos    = (int*)(ws + 1048576);      //   400,000
  int*   bsum    = (int*)(ws + 1462272);      //       392
  short* wf1     = (short*)(ws + 1572864);    //   622,592
  short* wf2     = (short*)(ws + 2359296);    //    49,152
  int*   esorted = (int*)(ws + 2621440);      // 1,600,000  (ends 4,221,440)
  short* t1      = (short*)(ws + 4300800);    // 51,200,000 (ends 55,500,800)
  short* t2h     = (short*)(ws + 55500800);   // 51,200,000 (ends 106,700,800); becomes h in-place
  float* u       = (float*)(ws + 4300800);    // 38,400,000 — t1 dead after gather1

  hipMemsetAsync(cnt, 0, (size_t)NN * sizeof(int), stream);
  hipMemsetAsync(epos, 0, (size_t)NN * sizeof(int), stream);
  k_prep_w1<<<(32 * 19 * 512 + 255) / 256, 256, 0, stream>>>(Wl1, Wr1, wf1);
  k_prep_w2<<<(6 * 8 * 512 + 255) / 256, 256, 0, stream>>>(Wl2, Wr2, wf2);
  k_count<<<(NE + 255) / 256, 256, 0, stream>>>(dstp, cnt);
  k_scan_local<<<NB_SCAN, 1024, 0, stream>>>(cnt, rowptr, bsum);
  k_scan_bsum<<<1, 128, 0, stream>>>(bsum);
  k_scan_add<<<NB_SCAN, 1024, 0, stream>>>(rowptr, bsum);
  k_sort<<<(NE + 255) / 256, 256, 0, stream>>>(src, dstp, rowptr, epos, esorted);
  k_gemm_l1<<<(NN + 63) / 64, 256, 0, stream>>>(x, wf1, t1, t2h);
  k_gather1<<<(NN * 64) / 256, 256, 0, stream>>>(t1, t2h, rowptr, esorted, bl1);
  k_gemm2<<<(NN + 127) / 128, 256, 0, stream>>>(t2h, wf2, u);
  k_final<<<(NN * 64) / 256, 256, 0, stream>>>(u, rowptr, esorted, bl2, out);
}

// Round 8
// 641.195 us; speedup vs baseline: 1.2978x; 1.1045x over previous
//
#include <hip/hip_runtime.h>
#include <stdint.h>

#define NN 100000
#define NE 400000
#define FIN 602
#define HID 256
#define NC 42
#define NB_SCAN 98   // ceil(NN/1024)

typedef __attribute__((ext_vector_type(8))) short bf16x8;
typedef __attribute__((ext_vector_type(4))) float f32x4;
typedef __attribute__((ext_vector_type(2))) float f32x2;
typedef __attribute__((ext_vector_type(4))) short s16x4;

static __device__ __forceinline__ short f2bf(float f) {
  union { float f; uint32_t u; } v; v.f = f;
  uint32_t r = (v.u + 0x7fffu + ((v.u >> 16) & 1u)) >> 16;
  return (short)(uint16_t)r;
}
static __device__ __forceinline__ float bf2f(short s) {
  union { uint32_t u; float f; } v; v.u = ((uint32_t)(uint16_t)s) << 16;
  return v.f;
}
// HW packed f32->bf16 (RNE)
static __device__ __forceinline__ uint32_t cvtpk(float a, float b) {
  uint32_t r;
  asm("v_cvt_pk_bf16_f32 %0, %1, %2" : "=v"(r) : "v"(a), "v"(b));
  return r;
}
static __device__ __forceinline__ bf16x8 pack8q(f32x4 a, f32x4 b) {
  union { bf16x8 v; uint32_t u[4]; } r;
  r.u[0] = cvtpk(a[0], a[1]);
  r.u[1] = cvtpk(a[2], a[3]);
  r.u[2] = cvtpk(b[0], b[1]);
  r.u[3] = cvtpk(b[2], b[3]);
  return r.v;
}
// async global->LDS, 4 bytes per lane, LDS dest = ldsbase + lane*4 (wave-uniform base)
static __device__ __forceinline__ void gload_lds4(const float* g, float* lds) {
  __builtin_amdgcn_global_load_lds((const __attribute__((address_space(1))) void*)g,
                                   (__attribute__((address_space(3))) void*)lds, 4, 0, 0);
}

// ---------------- degree count ----------------
__global__ __launch_bounds__(256) void k_count(const int* __restrict__ dst, int* __restrict__ cnt) {
  int t = blockIdx.x * 256 + threadIdx.x;
  if (t < NE) atomicAdd(&cnt[dst[t]], 1);
}

// ---------------- scan: rowptr = exclusive prefix of cnt ----------------
__global__ __launch_bounds__(1024) void k_scan_local(const int* __restrict__ cnt, int* __restrict__ rowptr,
                                                     int* __restrict__ bsum) {
  __shared__ int sm[1024];
  int tid = threadIdx.x, t = blockIdx.x * 1024 + tid;
  int v = (t < NN) ? cnt[t] : 0;
  sm[tid] = v;
  __syncthreads();
  for (int off = 1; off < 1024; off <<= 1) {
    int y = (tid >= off) ? sm[tid - off] : 0;
    __syncthreads();
    sm[tid] += y;
    __syncthreads();
  }
  if (t < NN) rowptr[t] = sm[tid] - v;  // local exclusive
  if (tid == 1023) bsum[blockIdx.x] = sm[tid];
}
__global__ __launch_bounds__(128) void k_scan_bsum(int* __restrict__ bsum) {
  __shared__ int sm[128];
  int tid = threadIdx.x;
  int v = (tid < NB_SCAN) ? bsum[tid] : 0;
  sm[tid] = v;
  __syncthreads();
  for (int off = 1; off < 128; off <<= 1) {
    int y = (tid >= off) ? sm[tid - off] : 0;
    __syncthreads();
    sm[tid] += y;
    __syncthreads();
  }
  if (tid < NB_SCAN) bsum[tid] = sm[tid] - v;  // exclusive
}
__global__ __launch_bounds__(1024) void k_scan_add(int* __restrict__ rowptr, const int* __restrict__ bsum) {
  int t = blockIdx.x * 1024 + threadIdx.x;
  if (t < NN) rowptr[t] += bsum[t >> 10];
  if (t == 0) rowptr[NN] = NE;
}

// ---------------- bucket sort edges by dst: esorted[j] = src ----------------
__global__ __launch_bounds__(256) void k_sort(const int* __restrict__ src, const int* __restrict__ dst,
                                              const int* __restrict__ rowptr, int* __restrict__ epos,
                                              int* __restrict__ esorted) {
  int t = blockIdx.x * 256 + threadIdx.x;
  if (t >= NE) return;
  int d = dst[t];
  int p = atomicAdd(&epos[d], 1);
  esorted[rowptr[d] + p] = src[t];
}

// ------------- weight prep: fragment-ordered bf16, K padded to 640 -------------
// wf[(((ct*20)+ks)*64 + lane)*8 + i] = W[k = ks*32 + (lane>>4)*8 + i][c = ct*16 + (lane&15)]
// ct in [0,16): Wl (cols 0..255); ct in [16,32): Wr (cols 256..511). k>=602 -> 0.
__global__ __launch_bounds__(256) void k_prep_w1(const float* __restrict__ Wl, const float* __restrict__ Wr,
                                                 short* __restrict__ wf) {
  int idx = blockIdx.x * 256 + threadIdx.x;
  if (idx >= 32 * 20 * 512) return;
  int i = idx & 7, l = (idx >> 3) & 63, rest = idx >> 9;
  int ks = rest % 20, ct = rest / 20;
  int c = ct * 16 + (l & 15);
  int k = ks * 32 + ((l >> 4) << 3) + i;
  float v = 0.f;
  if (k < FIN) v = (c < HID) ? Wl[k * HID + c] : Wr[k * HID + (c - HID)];
  wf[idx] = f2bf(v);
}
__global__ __launch_bounds__(256) void k_prep_w2(const float* __restrict__ Wl, const float* __restrict__ Wr,
                                                 short* __restrict__ wf) {
  int idx = blockIdx.x * 256 + threadIdx.x;
  if (idx >= 6 * 8 * 512) return;
  int i = idx & 7, l = (idx >> 3) & 63, rest = idx >> 9;
  int ks = rest & 7, ct = rest >> 3;
  int c = ct * 16 + (l & 15);
  int k = ks * 32 + ((l >> 4) << 3) + i;
  float v = 0.f;
  if (c < NC) v = Wl[k * NC + c];
  else if (c < 2 * NC) v = Wr[k * NC + (c - NC)];
  wf[idx] = f2bf(v);
}

// -------- layer-1 GEMM: bn=0: t1 = bf16(x@Wl1); bn=1: t2 = bf16(x@Wr1) --------
// grid (1563, 2). Block: 64 rows x 256 cols, 4 waves as 2x2 (wr=row-half, wc=col-half).
// Wave: acc[2][8] = 64 AGPR (2 waves/SIMD). BK=64, LDS double-buffered 2x16KB.
// VMEM ISSUE ORDER PER ITER (FIFO-critical): [16 weight b128] -> [16 stage gload_lds].
// Weight-use waits vmcnt(24)/vmcnt(16) keeping the stage in flight; the barrier's
// vmcnt(0) drain is covered by ds_read+pack+MFMA work.
// LDS swizzle: 16B-quad pq = lq ^ (row&15) (involution; stage pre-swizzles global k).
__global__ __launch_bounds__(256) void k_gemm_l1(const float* __restrict__ x, const short* __restrict__ wf,
                                                 short* __restrict__ t1, short* __restrict__ t2) {
  __shared__ float xs[2][64 * 64];  // 2 x 16KB
  const int lane = threadIdx.x & 63;
  const int w = threadIdx.x >> 6;
  const int lr = lane & 15, lg = lane >> 4;
  const int wc = w & 1, wr = w >> 1;
  const int row0 = blockIdx.x * 64;
  const int bn = blockIdx.y;  // 0 -> Wl/t1, 1 -> Wr/t2

  f32x4 acc[2][8];
#pragma unroll
  for (int a = 0; a < 2; ++a)
#pragma unroll
    for (int b = 0; b < 8; ++b)
      acc[a][b] = (f32x4){0.f, 0.f, 0.f, 0.f};

  const short* wb = wf + (size_t)(bn * 16 + wc * 8) * 20 * 512 + lane * 8;

  const int s_pq = lane >> 2, s_pe = lane & 3;

#define STAGE(KS, BUF)                                                             \
  {                                                                                \
    _Pragma("unroll")                                                              \
    for (int q = 0; q < 16; ++q) {                                                 \
      int r = w * 16 + q;                                                          \
      int rs = row0 + r; rs = rs < NN ? rs : NN - 1;                               \
      int ld = ((s_pq ^ (r & 15)) << 2) | s_pe;                                    \
      int k = (KS) * 64 + ld; k = k < FIN ? k : 0;                                 \
      gload_lds4(x + (size_t)rs * FIN + k, &xs[BUF][r * 64]);                      \
    }                                                                              \
  }

  STAGE(0, 0);
  __syncthreads();

  for (int ks = 0; ks < 10; ++ks) {
    const int cur = ks & 1;
    // (1) weight loads FIRST (both substeps)
    bf16x8 bb0[8], bb1[8];
#pragma unroll
    for (int c = 0; c < 8; ++c) bb0[c] = *(const bf16x8*)(wb + (size_t)(c * 20 + ks * 2) * 512);
#pragma unroll
    for (int c = 0; c < 8; ++c) bb1[c] = *(const bf16x8*)(wb + (size_t)(c * 20 + ks * 2 + 1) * 512);
    // (2) stage next K-tile (stays in flight across the MFMA work)
    if (ks < 9) STAGE(ks + 1, cur ^ 1);
    // (3) two 32-wide substeps from LDS
#pragma unroll
    for (int s = 0; s < 2; ++s) {
      bf16x8 af[2];
#pragma unroll
      for (int t = 0; t < 2; ++t) {
        int row = wr * 32 + t * 16 + lr;
        const char* rowp = (const char*)&xs[cur][row * 64];
        int lq0 = s * 8 + lg * 2;
        f32x4 v0 = *(const f32x4*)(rowp + ((((lq0 + 0) ^ lr) & 15) << 4));
        f32x4 v1 = *(const f32x4*)(rowp + ((((lq0 + 1) ^ lr) & 15) << 4));
        af[t] = pack8q(v0, v1);
      }
#pragma unroll
      for (int c = 0; c < 8; ++c) {
        bf16x8 bbv = s ? bb1[c] : bb0[c];
#pragma unroll
        for (int t = 0; t < 2; ++t)
          acc[t][c] = __builtin_amdgcn_mfma_f32_16x16x32_bf16(af[t], bbv, acc[t][c], 0, 0, 0);
      }
    }
    __syncthreads();
  }
#undef STAGE

  short* dstb = (bn == 0) ? t1 : t2;
#pragma unroll
  for (int t = 0; t < 2; ++t)
#pragma unroll
    for (int c = 0; c < 8; ++c)
#pragma unroll
      for (int j = 0; j < 4; ++j) {
        int row = row0 + wr * 32 + t * 16 + lg * 4 + j;
        if (row < NN) {
          int col = (wc * 8 + c) * 16 + lr;
          dstb[(size_t)row * HID + col] = f2bf(acc[t][c][j]);
        }
      }
}

// ---- gather1 (fused combine): h = relu(mean(t1[nbrs]) + bl1 + t2[n]), IN-PLACE over t2 ----
// 4-deep manual load pipeline: 4 independent row loads in flight per step.
__global__ __launch_bounds__(256) void k_gather1(const short* __restrict__ t1, short* __restrict__ t2h,
                                                 const int* __restrict__ rowptr, const int* __restrict__ esorted,
                                                 const float* __restrict__ bl) {
  int t = blockIdx.x * 256 + threadIdx.x;
  int n = t >> 6, lane = t & 63;
  if (n >= NN) return;
  s16x4 tv = *(const s16x4*)(t2h + (size_t)n * HID + lane * 4);  // own row, read before write
  int beg = rowptr[n], end = rowptr[n + 1];
  float a0 = 0.f, a1 = 0.f, a2 = 0.f, a3 = 0.f;
  int j = beg;
  for (; j + 4 <= end; j += 4) {
    int s0 = esorted[j], s1 = esorted[j + 1], s2 = esorted[j + 2], s3 = esorted[j + 3];
    s16x4 v0 = *(const s16x4*)(t1 + (size_t)s0 * HID + lane * 4);
    s16x4 v1 = *(const s16x4*)(t1 + (size_t)s1 * HID + lane * 4);
    s16x4 v2 = *(const s16x4*)(t1 + (size_t)s2 * HID + lane * 4);
    s16x4 v3 = *(const s16x4*)(t1 + (size_t)s3 * HID + lane * 4);
    a0 += bf2f(v0[0]) + bf2f(v1[0]) + bf2f(v2[0]) + bf2f(v3[0]);
    a1 += bf2f(v0[1]) + bf2f(v1[1]) + bf2f(v2[1]) + bf2f(v3[1]);
    a2 += bf2f(v0[2]) + bf2f(v1[2]) + bf2f(v2[2]) + bf2f(v3[2]);
    a3 += bf2f(v0[3]) + bf2f(v1[3]) + bf2f(v2[3]) + bf2f(v3[3]);
  }
  for (; j < end; ++j) {
    int s = esorted[j];
    s16x4 v = *(const s16x4*)(t1 + (size_t)s * HID + lane * 4);
    a0 += bf2f(v[0]); a1 += bf2f(v[1]); a2 += bf2f(v[2]); a3 += bf2f(v[3]);
  }
  int deg = end - beg;
  float inv = 1.0f / (float)(deg > 1 ? deg : 1);
  f32x4 b = *(const f32x4*)(bl + lane * 4);
  s16x4 o;
  float v0 = a0 * inv + b[0] + bf2f(tv[0]);
  float v1 = a1 * inv + b[1] + bf2f(tv[1]);
  float v2 = a2 * inv + b[2] + bf2f(tv[2]);
  float v3 = a3 * inv + b[3] + bf2f(tv[3]);
  o[0] = f2bf(v0 > 0.f ? v0 : 0.f);
  o[1] = f2bf(v1 > 0.f ? v1 : 0.f);
  o[2] = f2bf(v2 > 0.f ? v2 : 0.f);
  o[3] = f2bf(v3 > 0.f ? v3 : 0.f);
  *(s16x4*)(t2h + (size_t)n * HID + lane * 4) = o;
}

// ---------------- GEMM2: u[N,96] = h[N,256] @ [Wl2|Wr2] (cols 84..95 pad) ----------------
__global__ __launch_bounds__(256) void k_gemm2(const short* __restrict__ h, const short* __restrict__ wf,
                                               float* __restrict__ u) {
  const int lane = threadIdx.x & 63;
  const int w = threadIdx.x >> 6;
  const int lr = lane & 15, lg = lane >> 4;
  const int row0 = blockIdx.x * 128 + w * 32;

  f32x4 acc[2][6];
#pragma unroll
  for (int a = 0; a < 2; ++a)
#pragma unroll
    for (int b = 0; b < 6; ++b)
      acc[a][b] = (f32x4){0.f, 0.f, 0.f, 0.f};

  const int r0 = row0 + lr, r1 = row0 + 16 + lr;
#pragma unroll
  for (int ks = 0; ks < 8; ++ks) {
    bf16x8 a0, a1;
#pragma unroll
    for (int i = 0; i < 8; ++i) { a0[i] = 0; a1[i] = 0; }
    if (r0 < NN) a0 = *(const bf16x8*)(h + (size_t)r0 * HID + ks * 32 + lg * 8);
    if (r1 < NN) a1 = *(const bf16x8*)(h + (size_t)r1 * HID + ks * 32 + lg * 8);
    bf16x8 bfrag[6];
#pragma unroll
    for (int ct = 0; ct < 6; ++ct)
      bfrag[ct] = *(const bf16x8*)(wf + (size_t)((ct * 8 + ks) * 64 + lane) * 8);
#pragma unroll
    for (int ct = 0; ct < 6; ++ct) {
      acc[0][ct] = __builtin_amdgcn_mfma_f32_16x16x32_bf16(a0, bfrag[ct], acc[0][ct], 0, 0, 0);
      acc[1][ct] = __builtin_amdgcn_mfma_f32_16x16x32_bf16(a1, bfrag[ct], acc[1][ct], 0, 0, 0);
    }
  }
#pragma unroll
  for (int rt = 0; rt < 2; ++rt)
#pragma unroll
    for (int ct = 0; ct < 6; ++ct)
#pragma unroll
      for (int j = 0; j < 4; ++j) {
        int row = row0 + rt * 16 + lg * 4 + j;
        int col = ct * 16 + lr;
        if (row < NN) u[(size_t)row * 96 + col] = acc[rt][ct][j];
      }
}

// ---------------- final: log_softmax(mean(u[nbrs,0:42]) + bl2 + u[:,42:84]) ----------------
__global__ __launch_bounds__(256) void k_final(const float* __restrict__ u, const int* __restrict__ rowptr,
                                               const int* __restrict__ esorted, const float* __restrict__ bl,
                                               float* __restrict__ out) {
  int t = blockIdx.x * 256 + threadIdx.x;
  int n = t >> 6, c = t & 63;
  if (n >= NN) return;
  int beg = rowptr[n], end = rowptr[n + 1];
  float a = 0.f;
  if (c < NC) {
    int j = beg;
    for (; j + 4 <= end; j += 4) {
      int s0 = esorted[j], s1 = esorted[j + 1], s2 = esorted[j + 2], s3 = esorted[j + 3];
      float u0 = u[(size_t)s0 * 96 + c];
      float u1 = u[(size_t)s1 * 96 + c];
      float u2 = u[(size_t)s2 * 96 + c];
      float u3 = u[(size_t)s3 * 96 + c];
      a += (u0 + u1) + (u2 + u3);
    }
    for (; j < end; ++j) a += u[(size_t)esorted[j] * 96 + c];
  }
  int deg = end - beg;
  float inv = 1.0f / (float)(deg > 1 ? deg : 1);
  float v = (c < NC) ? (a * inv + bl[c] + u[(size_t)n * 96 + NC + c]) : -1e30f;
  float m = v;
#pragma unroll
  for (int off = 32; off > 0; off >>= 1) m = fmaxf(m, __shfl_xor(m, off));
  float e = (c < NC) ? __expf(v - m) : 0.f;
#pragma unroll
  for (int off = 32; off > 0; off >>= 1) e += __shfl_xor(e, off);
  float lse = __logf(e);
  if (c < NC) out[(size_t)n * NC + c] = v - m - lse;
}

extern "C" void kernel_launch(void* const* d_in, const int* in_sizes, int n_in,
                              void* d_out, int out_size, void* d_ws, size_t ws_size,
                              hipStream_t stream) {
  const float* x   = (const float*)d_in[0];
  const int* eidx  = (const int*)d_in[1];
  const float* Wl1 = (const float*)d_in[2];
  const float* bl1 = (const float*)d_in[3];
  const float* Wr1 = (const float*)d_in[4];
  const float* Wl2 = (const float*)d_in[5];
  const float* bl2 = (const float*)d_in[6];
  const float* Wr2 = (const float*)d_in[7];
  float* out = (float*)d_out;
  const int* src = eidx;
  const int* dstp = eidx + NE;

  // workspace layout (bytes) — peak 106,700,800 B (validated footprint)
  char* ws = (char*)d_ws;
  int*   cnt     = (int*)(ws + 0);            //   400,000
  int*   rowptr  = (int*)(ws + 524288);       //   400,004
  int*   epos    = (int*)(ws + 1048576);      //   400,000
  int*   bsum    = (int*)(ws + 1462272);      //       392
  short* wf1     = (short*)(ws + 1572864);    //   655,360 (fits 786,432 slot)
  short* wf2     = (short*)(ws + 2359296);    //    49,152
  int*   esorted = (int*)(ws + 2621440);      // 1,600,000  (ends 4,221,440)
  short* t1      = (short*)(ws + 4300800);    // 51,200,000 (ends 55,500,800)
  short* t2h     = (short*)(ws + 55500800);   // 51,200,000 (ends 106,700,800); becomes h in-place
  float* u       = (float*)(ws + 4300800);    // 38,400,000 — t1 dead after gather1

  hipMemsetAsync(cnt, 0, (size_t)NN * sizeof(int), stream);
  hipMemsetAsync(epos, 0, (size_t)NN * sizeof(int), stream);
  k_prep_w1<<<(32 * 20 * 512 + 255) / 256, 256, 0, stream>>>(Wl1, Wr1, wf1);
  k_prep_w2<<<(6 * 8 * 512 + 255) / 256, 256, 0, stream>>>(Wl2, Wr2, wf2);
  k_count<<<(NE + 255) / 256, 256, 0, stream>>>(dstp, cnt);
  k_scan_local<<<NB_SCAN, 1024, 0, stream>>>(cnt, rowptr, bsum);
  k_scan_bsum<<<1, 128, 0, stream>>>(bsum);
  k_scan_add<<<NB_SCAN, 1024, 0, stream>>>(rowptr, bsum);
  k_sort<<<(NE + 255) / 256, 256, 0, stream>>>(src, dstp, rowptr, epos, esorted);
  dim3 g1((NN + 63) / 64, 2);
  k_gemm_l1<<<g1, 256, 0, stream>>>(x, wf1, t1, t2h);
  k_gather1<<<(NN * 64) / 256, 256, 0, stream>>>(t1, t2h, rowptr, esorted, bl1);
  k_gemm2<<<(NN + 127) / 128, 256, 0, stream>>>(t2h, wf2, u);
  k_final<<<(NN * 64) / 256, 256, 0, stream>>>(u, rowptr, esorted, bl2, out);
}